// Round 3
// baseline (460.886 us; speedup 1.0000x reference)
//
#include <hip/hip_runtime.h>
#include <hip/hip_bf16.h>

#define GN 8192
#define IN_DIM 512
#define ODIM 64
#define SLOPE 0.2f
#define NT2 2                  // tiles per attn block
#define JSPLIT2 8              // js0 groups (8 x 1024 cols)

typedef __attribute__((ext_vector_type(4))) float  f32x4;
typedef __attribute__((ext_vector_type(4))) int    i32x4;
typedef __attribute__((ext_vector_type(8))) short  bf16x8;
typedef __attribute__((ext_vector_type(4))) unsigned short u16x4;

static __device__ __forceinline__ float bf2f(unsigned short u) {
    return __uint_as_float(((unsigned)u) << 16);
}
static __device__ __forceinline__ unsigned short f2bf(float f) {
    union { float f; unsigned u; } c; c.f = f;
    unsigned b = c.u;
    return (unsigned short)((b + 0x7fffu + ((b >> 16) & 1u)) >> 16);  // RNE
}

// load 8 contiguous elements as bf16x8, from either wire dtype
static __device__ __forceinline__ bf16x8 load8(const void* p, size_t off, int f32) {
    if (f32) {
        f32x4 lo = *(const f32x4*)((const float*)p + off);
        f32x4 hi = *(const f32x4*)((const float*)p + off + 4);
        bf16x8 r;
        #pragma unroll
        for (int q = 0; q < 4; ++q) {
            r[q]     = (short)f2bf(lo[q]);
            r[4 + q] = (short)f2bf(hi[q]);
        }
        return r;
    }
    return *(const bf16x8*)((const ushort*)p + off);
}

// Kernel A: adj (int 0/1) -> bitmask, 1 bit per col. Pure coalesced stream:
// thread reads 32 consecutive ints (128B), writes one uint (32 bits).
// Per wave: 8KB contiguous read, 256B contiguous write. This isolates the
// 268MB HBM stream in a dependency-free kernel that trivially saturates BW
// (no vmcnt-consumer coupling possible).
extern "C" __global__ __launch_bounds__(256)
void gat_pack(const int* __restrict__ adj, unsigned* __restrict__ gbm)
{
    const size_t ui = (size_t)blockIdx.x * 256 + threadIdx.x;
    const int* p = adj + ui * 32;
    unsigned w = 0;
    #pragma unroll
    for (int c = 0; c < 8; ++c) {
        i32x4 v = ((const i32x4*)p)[c];
        #pragma unroll
        for (int q = 0; q < 4; ++q)
            w |= (v[q] > 0 ? 1u : 0u) << (c * 4 + q);
    }
    gbm[ui] = w;
}

// Kernel 1 (MFMA GEMM): Wh = x@W^T. Epilogue writes WhTp in B-operand-native
// layout (16B unit U(jblk,n) = Wh[jblk*8+0..7][n]); s; E1=e^{d}, E2=e^{0.2d}
// (separable-exp: exp monotone => exp(max(d+k1,0.2d+k2)) = max(e^{k1}E1,
// e^{k2}E2)); dmax, dflag; zero-inits accum/lsum.
extern "C" __global__ __launch_bounds__(256)
void gat_proj(const void* __restrict__ x_, const void* __restrict__ W_,
              const void* __restrict__ as_, const void* __restrict__ ad_,
              ushort* __restrict__ WhTp, float* __restrict__ s_arr,
              float* __restrict__ E1, float* __restrict__ E2,
              int* __restrict__ dmax_bits, int* __restrict__ dflag,
              float* __restrict__ accum, float* __restrict__ lsum)
{
    {
        f32x4 z = {0.f, 0.f, 0.f, 0.f};
        f32x4* ap = (f32x4*)(accum + (size_t)blockIdx.x * 4096);
        #pragma unroll
        for (int k = 0; k < 4; ++k) ap[k * 256 + threadIdx.x] = z;
        if (threadIdx.x < 64) lsum[blockIdx.x * 64 + threadIdx.x] = 0.f;
    }
    const int wave = threadIdx.x >> 6;
    const int lane = threadIdx.x & 63;
    unsigned xw = ((const unsigned*)x_)[lane];
    unsigned ef = (xw >> 23) & 0xffu;
    unsigned long long vt = __ballot(ef > 60u && ef < 180u);
    const int f32 = (__popcll(vt) >= 32) ? 1 : 0;
    if (blockIdx.x == 0 && threadIdx.x == 0) *dflag = f32;

    const int quad = lane >> 4;
    const int lq   = lane & 15;
    const int i0   = blockIdx.x * 64 + wave * 16;

    f32x4 acc[4] = {{0,0,0,0},{0,0,0,0},{0,0,0,0},{0,0,0,0}};
    const size_t arow = (size_t)(i0 + lq) * IN_DIM;
    #pragma unroll 2
    for (int k0 = 0; k0 < IN_DIM; k0 += 32) {
        const int kk = k0 + quad * 8;
        bf16x8 a  = load8(x_, arow + kk, f32);
        bf16x8 b0 = load8(W_, (size_t)( 0 + lq) * IN_DIM + kk, f32);
        bf16x8 b1 = load8(W_, (size_t)(16 + lq) * IN_DIM + kk, f32);
        bf16x8 b2 = load8(W_, (size_t)(32 + lq) * IN_DIM + kk, f32);
        bf16x8 b3 = load8(W_, (size_t)(48 + lq) * IN_DIM + kk, f32);
        acc[0] = __builtin_amdgcn_mfma_f32_16x16x32_bf16(a, b0, acc[0], 0, 0, 0);
        acc[1] = __builtin_amdgcn_mfma_f32_16x16x32_bf16(a, b1, acc[1], 0, 0, 0);
        acc[2] = __builtin_amdgcn_mfma_f32_16x16x32_bf16(a, b2, acc[2], 0, 0, 0);
        acc[3] = __builtin_amdgcn_mfma_f32_16x16x32_bf16(a, b3, acc[3], 0, 0, 0);
    }
    float av_s[4], av_d[4];
    #pragma unroll
    for (int t = 0; t < 4; ++t) {
        const int n = t * 16 + lq;
        av_s[t] = f32 ? ((const float*)as_)[n] : bf2f(((const ushort*)as_)[n]);
        av_d[t] = f32 ? ((const float*)ad_)[n] : bf2f(((const ushort*)ad_)[n]);
    }
    #pragma unroll
    for (int t = 0; t < 4; ++t) {
        u16x4 pk;
        #pragma unroll
        for (int r = 0; r < 4; ++r) pk[r] = f2bf(acc[t][r]);
        const size_t hw = ((size_t)((i0 >> 3) + (quad >> 1)) * 64 + t * 16 + lq) * 8
                          + (quad & 1) * 4;
        *(u16x4*)(WhTp + hw) = pk;
    }
    float ps[4], pd[4];
    #pragma unroll
    for (int r = 0; r < 4; ++r) {
        float s = 0.f, d = 0.f;
        #pragma unroll
        for (int t = 0; t < 4; ++t) {
            s = fmaf(acc[t][r], av_s[t], s);
            d = fmaf(acc[t][r], av_d[t], d);
        }
        #pragma unroll
        for (int off = 1; off < 16; off <<= 1) {
            s += __shfl_xor(s, off);
            d += __shfl_xor(d, off);
        }
        ps[r] = s; pd[r] = d;
    }
    if (lq == 0) {
        float dmx = -1e30f;
        #pragma unroll
        for (int r = 0; r < 4; ++r) {
            const int n = i0 + quad * 4 + r;
            const float dv = pd[r];
            s_arr[n] = ps[r];
            E1[n] = __expf(fminf(dv, 87.f));        // e^{dj} (clamped vs inf)
            E2[n] = __expf(SLOPE * dv);             // e^{0.2 dj}
            dmx = fmaxf(dmx, dv);
        }
        if (dmx > 0.f) atomicMax(dmax_bits, __float_as_int(dmx));
    }
}

// Kernel 2: attention from the bitmask. 1024 blocks = 128 ib x 8 js0, each
// block: 64 rows x 1024 cols (2 tiles x 16 col-iters). ZERO HBM streaming
// inside: bitmask 4B/lane-group/iter (L2 after first touch), WhTp fragments
// (1MB, L2), E tables in LDS. All load latencies ~200cy -> lag-1 rolling
// prefetch covers; no rings, no in-loop barriers, ~90 VGPR.
// w = mask_bit ? max(Aw*E1[j], Bw*E2[j]) : 0  (separable exp, no transcend.)
extern "C" __global__ __launch_bounds__(256)
void gat_attn(const unsigned char* __restrict__ gbm,
              const ushort* __restrict__ WhTp,
              const float* __restrict__ s_arr,
              const float* __restrict__ E1, const float* __restrict__ E2,
              const int* __restrict__ dmax_bits,
              float* __restrict__ accum, float* __restrict__ lsum)
{
    __shared__ float lE[2 * NT2 * 512];   // 8KB: [0..1023]=E1 slice, [1024..]=E2
    const int b    = blockIdx.x;        // 0..1023
    const int ib   = b & 127;
    const int js0  = b >> 7;            // 0..7
    const int wave = threadIdx.x >> 6;
    const int lane = threadIdx.x & 63;
    const int quad = lane >> 4;
    const int lq   = lane & 15;
    const int i0   = ib * 64;
    const int i    = i0 + wave * 16 + lq;

    // stage E slice (this js0's 2 tiles = 1024 cols) into LDS
    {
        const int m0 = threadIdx.x * 4;                   // 0..1020
        const int gcol = (js0 * NT2 + (m0 >> 9)) * 512 + (m0 & 511);
        *(f32x4*)&lE[m0]        = *(const f32x4*)(E1 + gcol);
        *(f32x4*)&lE[1024 + m0] = *(const f32x4*)(E2 + gcol);
    }

    const float dmax = __int_as_float(*dmax_bits);
    const float si  = s_arr[i];
    const float tbv = si + dmax;
    const float mi  = fmaxf(tbv, SLOPE * tbv);   // row-logit upper bound
    const float Aw  = __expf(si - mi);           // e^{k1}
    const float Bw  = __expf(SLOPE * si - mi);   // e^{k2}

    // bitmask row for this lane's A-fragment row (quad selects bits, not addr)
    const unsigned char* mrow = gbm + (size_t)i * (GN / 8);
    const int colbase = js0 * NT2 * 512;

    f32x4 acc0 = {0,0,0,0}, acc1 = {0,0,0,0}, acc2 = {0,0,0,0}, acc3 = {0,0,0,0};
    f32x4 acc4 = {0,0,0,0};              // row-sum via ones-MFMA
    bf16x8 ones;
    #pragma unroll
    for (int q = 0; q < 8; ++q) ones[q] = (short)0x3F80;

    // u = t*16+it, col(u) = colbase + u*32 (contiguous walk; u*32 spans tiles)
    // preload u=0
    unsigned bm = *(const unsigned*)(mrow + (colbase >> 3));
    bf16x8 b0, b1, b2, b3;
    {
        const int col = colbase;
        const ushort* nb = WhTp + ((size_t)(col >> 3) + quad) * 512;
        b0 = *(const bf16x8*)(nb + ( 0 + lq) * 8);
        b1 = *(const bf16x8*)(nb + (16 + lq) * 8);
        b2 = *(const bf16x8*)(nb + (32 + lq) * 8);
        b3 = *(const bf16x8*)(nb + (48 + lq) * 8);
    }
    __syncthreads();   // lE staged

    #pragma unroll 1
    for (int t = 0; t < NT2; ++t) {
        #pragma unroll
        for (int it = 0; it < 16; ++it) {
            const int u = t * 16 + it;
            // rolling lag-1 prefetch (all L2-resident; ~200cy latency)
            const int un   = (u < NT2 * 16 - 1) ? u + 1 : u;
            const int ncol = colbase + un * 32;
            const unsigned nbm = *(const unsigned*)(mrow + (ncol >> 3));
            const ushort* nb = WhTp + ((size_t)(ncol >> 3) + quad) * 512;
            const bf16x8 nb0 = *(const bf16x8*)(nb + ( 0 + lq) * 8);
            const bf16x8 nb1 = *(const bf16x8*)(nb + (16 + lq) * 8);
            const bf16x8 nb2 = *(const bf16x8*)(nb + (32 + lq) * 8);
            const bf16x8 nb3 = *(const bf16x8*)(nb + (48 + lq) * 8);
            // E slices from LDS
            const float* pe = lE + u * 32 + quad * 8;
            const f32x4 e1a = *(const f32x4*)pe;
            const f32x4 e1b = *(const f32x4*)(pe + 4);
            const f32x4 e2a = *(const f32x4*)(pe + 1024);
            const f32x4 e2b = *(const f32x4*)(pe + 1028);
            // weights: w = bit ? max(Aw*E1, Bw*E2) : 0
            const unsigned m8 = (bm >> (quad * 8)) & 0xffu;
            float w[8];
            #pragma unroll
            for (int q = 0; q < 4; ++q) {
                const float w0 = fmaxf(Aw * e1a[q], Bw * e2a[q]);
                const float w1 = fmaxf(Aw * e1b[q], Bw * e2b[q]);
                w[q]     = ((m8 >> q) & 1u) ? w0 : 0.f;
                w[4 + q] = ((m8 >> (4 + q)) & 1u) ? w1 : 0.f;
            }
            union { bf16x8 v; __hip_bfloat162 h[4]; } af;
            #pragma unroll
            for (int q = 0; q < 4; ++q)
                af.h[q] = __float22bfloat162_rn(make_float2(w[2 * q], w[2 * q + 1]));
            acc0 = __builtin_amdgcn_mfma_f32_16x16x32_bf16(af.v, b0, acc0, 0, 0, 0);
            acc1 = __builtin_amdgcn_mfma_f32_16x16x32_bf16(af.v, b1, acc1, 0, 0, 0);
            acc2 = __builtin_amdgcn_mfma_f32_16x16x32_bf16(af.v, b2, acc2, 0, 0, 0);
            acc3 = __builtin_amdgcn_mfma_f32_16x16x32_bf16(af.v, b3, acc3, 0, 0, 0);
            acc4 = __builtin_amdgcn_mfma_f32_16x16x32_bf16(af.v, ones, acc4, 0, 0, 0);
            bm = nbm; b0 = nb0; b1 = nb1; b2 = nb2; b3 = nb3;
        }
    }

    // epilogue: C/D col=lq, row=quad*4+r; acc4 holds row sums in every col
    const int orow = i0 + wave * 16 + quad * 4;
    if (lq == 0) {
        #pragma unroll
        for (int r = 0; r < 4; ++r) atomicAdd(&lsum[orow + r], acc4[r]);
    }
    #pragma unroll
    for (int r = 0; r < 4; ++r) {
        atomicAdd(&accum[(size_t)(orow + r) * ODIM +  0 + lq], acc0[r]);
        atomicAdd(&accum[(size_t)(orow + r) * ODIM + 16 + lq], acc1[r]);
        atomicAdd(&accum[(size_t)(orow + r) * ODIM + 32 + lq], acc2[r]);
        atomicAdd(&accum[(size_t)(orow + r) * ODIM + 48 + lq], acc3[r]);
    }
}

// Kernel 3: out = (accum / lsum), dtype per flag
extern "C" __global__ __launch_bounds__(256)
void gat_final(const float* __restrict__ accum, const float* __restrict__ lsum,
               const int* __restrict__ flag, void* __restrict__ out)
{
    const int idx = blockIdx.x * 256 + threadIdx.x;
    const float v = accum[idx] / lsum[idx >> 6];
    if (*flag) ((float*)out)[idx] = v;
    else       ((ushort*)out)[idx] = f2bf(v);
}

extern "C" void kernel_launch(void* const* d_in, const int* in_sizes, int n_in,
                              void* d_out, int out_size, void* d_ws, size_t ws_size,
                              hipStream_t stream)
{
    const void* x     = d_in[0];
    const int*  adj   = (const int*)d_in[1];
    const void* W     = d_in[2];
    const void* a_src = d_in[3];
    const void* a_dst = d_in[4];

    char* ws = (char*)d_ws;
    size_t off = 0;
    int* dmax_bits = (int*)(ws + off);  off += 128;
    int* dflag = (int*)(ws + off);      off += 128;
    size_t zero_bytes = off;                                               // 256 B only
    float* accum = (float*)(ws + off);  off += (size_t)GN * ODIM * 4;      // 2 MB (proj zeroes)
    float* lsum  = (float*)(ws + off);  off += (size_t)GN * 4;             // 32 KB (proj zeroes)
    float* s_arr = (float*)(ws + off);  off += (size_t)GN * 4;
    float* E1    = (float*)(ws + off);  off += (size_t)GN * 4;
    float* E2    = (float*)(ws + off);  off += (size_t)GN * 4;
    ushort* WhTp = (ushort*)(ws + off); off += (size_t)ODIM * GN * 2;      // 1 MB
    unsigned* gbm = (unsigned*)(ws + off); off += (size_t)GN * (GN / 8);   // 8 MB

    hipMemsetAsync(ws, 0, zero_bytes, stream);
    gat_pack<<<GN * (GN / 32) / 256, 256, 0, stream>>>(adj, gbm);          // 8192 blocks
    gat_proj<<<GN / 64, 256, 0, stream>>>(x, W, a_src, a_dst,
                                          WhTp, s_arr, E1, E2, dmax_bits, dflag,
                                          accum, lsum);
    gat_attn<<<128 * JSPLIT2, 256, 0, stream>>>((const unsigned char*)gbm, WhTp,
                                                s_arr, E1, E2, dmax_bits,
                                                accum, lsum);
    gat_final<<<GN * ODIM / 256, 256, 0, stream>>>(accum, lsum, dflag, d_out);
}

// Round 4
// 455.181 us; speedup vs baseline: 1.0125x; 1.0125x over previous
//
#include <hip/hip_runtime.h>
#include <hip/hip_bf16.h>

#define GN 8192
#define IN_DIM 512
#define ODIM 64
#define SLOPE 0.2f
#define KSPL 4                 // column split: 4 disjoint partial slabs
#define KCOLS (GN / KSPL)      // 2048 cols per attn block
#define KITER (KCOLS / 32)     // 64 col-iters per block

typedef __attribute__((ext_vector_type(4))) float  f32x4;
typedef __attribute__((ext_vector_type(4))) int    i32x4;
typedef __attribute__((ext_vector_type(8))) short  bf16x8;
typedef __attribute__((ext_vector_type(4))) unsigned short u16x4;

static __device__ __forceinline__ float bf2f(unsigned short u) {
    return __uint_as_float(((unsigned)u) << 16);
}
static __device__ __forceinline__ unsigned short f2bf(float f) {
    union { float f; unsigned u; } c; c.f = f;
    unsigned b = c.u;
    return (unsigned short)((b + 0x7fffu + ((b >> 16) & 1u)) >> 16);  // RNE
}

// load 8 contiguous elements as bf16x8, from either wire dtype
static __device__ __forceinline__ bf16x8 load8(const void* p, size_t off, int f32) {
    if (f32) {
        f32x4 lo = *(const f32x4*)((const float*)p + off);
        f32x4 hi = *(const f32x4*)((const float*)p + off + 4);
        bf16x8 r;
        #pragma unroll
        for (int q = 0; q < 4; ++q) {
            r[q]     = (short)f2bf(lo[q]);
            r[4 + q] = (short)f2bf(hi[q]);
        }
        return r;
    }
    return *(const bf16x8*)((const ushort*)p + off);
}

// Kernel A: adj (int 0/1) -> bitmask, 1 bit per col. Pure coalesced stream,
// dependency-free, saturates HBM BW (~45us for 268MB).
extern "C" __global__ __launch_bounds__(256)
void gat_pack(const int* __restrict__ adj, unsigned* __restrict__ gbm)
{
    const size_t ui = (size_t)blockIdx.x * 256 + threadIdx.x;
    const int* p = adj + ui * 32;
    unsigned w = 0;
    #pragma unroll
    for (int c = 0; c < 8; ++c) {
        i32x4 v = ((const i32x4*)p)[c];
        #pragma unroll
        for (int q = 0; q < 4; ++q)
            w |= (v[q] > 0 ? 1u : 0u) << (c * 4 + q);
    }
    gbm[ui] = w;
}

// Kernel 1 (MFMA GEMM): Wh = x@W^T. Epilogue writes WhTp in B-operand-native
// layout; s_arr; E1=e^{d}, E2=e^{0.2d} (separable exp); dmax; dflag.
// (No accum/lsum zero-init anymore -- atomics are gone entirely.)
extern "C" __global__ __launch_bounds__(256)
void gat_proj(const void* __restrict__ x_, const void* __restrict__ W_,
              const void* __restrict__ as_, const void* __restrict__ ad_,
              ushort* __restrict__ WhTp, float* __restrict__ s_arr,
              float* __restrict__ E1, float* __restrict__ E2,
              int* __restrict__ dmax_bits, int* __restrict__ dflag)
{
    const int wave = threadIdx.x >> 6;
    const int lane = threadIdx.x & 63;
    unsigned xw = ((const unsigned*)x_)[lane];
    unsigned ef = (xw >> 23) & 0xffu;
    unsigned long long vt = __ballot(ef > 60u && ef < 180u);
    const int f32 = (__popcll(vt) >= 32) ? 1 : 0;
    if (blockIdx.x == 0 && threadIdx.x == 0) *dflag = f32;

    const int quad = lane >> 4;
    const int lq   = lane & 15;
    const int i0   = blockIdx.x * 64 + wave * 16;

    f32x4 acc[4] = {{0,0,0,0},{0,0,0,0},{0,0,0,0},{0,0,0,0}};
    const size_t arow = (size_t)(i0 + lq) * IN_DIM;
    #pragma unroll 2
    for (int k0 = 0; k0 < IN_DIM; k0 += 32) {
        const int kk = k0 + quad * 8;
        bf16x8 a  = load8(x_, arow + kk, f32);
        bf16x8 b0 = load8(W_, (size_t)( 0 + lq) * IN_DIM + kk, f32);
        bf16x8 b1 = load8(W_, (size_t)(16 + lq) * IN_DIM + kk, f32);
        bf16x8 b2 = load8(W_, (size_t)(32 + lq) * IN_DIM + kk, f32);
        bf16x8 b3 = load8(W_, (size_t)(48 + lq) * IN_DIM + kk, f32);
        acc[0] = __builtin_amdgcn_mfma_f32_16x16x32_bf16(a, b0, acc[0], 0, 0, 0);
        acc[1] = __builtin_amdgcn_mfma_f32_16x16x32_bf16(a, b1, acc[1], 0, 0, 0);
        acc[2] = __builtin_amdgcn_mfma_f32_16x16x32_bf16(a, b2, acc[2], 0, 0, 0);
        acc[3] = __builtin_amdgcn_mfma_f32_16x16x32_bf16(a, b3, acc[3], 0, 0, 0);
    }
    float av_s[4], av_d[4];
    #pragma unroll
    for (int t = 0; t < 4; ++t) {
        const int n = t * 16 + lq;
        av_s[t] = f32 ? ((const float*)as_)[n] : bf2f(((const ushort*)as_)[n]);
        av_d[t] = f32 ? ((const float*)ad_)[n] : bf2f(((const ushort*)ad_)[n]);
    }
    #pragma unroll
    for (int t = 0; t < 4; ++t) {
        u16x4 pk;
        #pragma unroll
        for (int r = 0; r < 4; ++r) pk[r] = f2bf(acc[t][r]);
        const size_t hw = ((size_t)((i0 >> 3) + (quad >> 1)) * 64 + t * 16 + lq) * 8
                          + (quad & 1) * 4;
        *(u16x4*)(WhTp + hw) = pk;
    }
    float ps[4], pd[4];
    #pragma unroll
    for (int r = 0; r < 4; ++r) {
        float s = 0.f, d = 0.f;
        #pragma unroll
        for (int t = 0; t < 4; ++t) {
            s = fmaf(acc[t][r], av_s[t], s);
            d = fmaf(acc[t][r], av_d[t], d);
        }
        #pragma unroll
        for (int off = 1; off < 16; off <<= 1) {
            s += __shfl_xor(s, off);
            d += __shfl_xor(d, off);
        }
        ps[r] = s; pd[r] = d;
    }
    if (lq == 0) {
        float dmx = -1e30f;
        #pragma unroll
        for (int r = 0; r < 4; ++r) {
            const int n = i0 + quad * 4 + r;
            const float dv = pd[r];
            s_arr[n] = ps[r];
            E1[n] = __expf(fminf(dv, 87.f));        // e^{dj} (clamped vs inf)
            E2[n] = __expf(SLOPE * dv);             // e^{0.2 dj}
            dmx = fmaxf(dmx, dv);
        }
        if (dmx > 0.f) atomicMax(dmax_bits, __float_as_int(dmx));
    }
}

// Kernel 2: attention, ZERO atomics. 512 blocks = 128 ib x 4 js0; each block
// owns rows [ib*64, ib*64+64) x cols [js0*2048, +2048) and writes a DISJOINT
// partial slab part[js0] + partial row-sums prs[js0] with plain stores.
// Sources: bitmask (L2), WhTp fragments (L2), E tables (LDS). No HBM stream,
// no __syncthreads in loop, lag-1 prefetch, unroll 4, launch_bounds(256,2)
// pins >=2 blocks/CU (8 waves/CU).
extern "C" __global__ __launch_bounds__(256, 2)
void gat_attn(const unsigned char* __restrict__ gbm,
              const ushort* __restrict__ WhTp,
              const float* __restrict__ s_arr,
              const float* __restrict__ E1, const float* __restrict__ E2,
              const int* __restrict__ dmax_bits,
              float* __restrict__ part, float* __restrict__ prs)
{
    __shared__ float lE[2 * KCOLS];   // 16KB: [0..2047]=E1 slice, [2048..]=E2
    const int b    = blockIdx.x;        // 0..511
    const int ib   = b & 127;
    const int js0  = b >> 7;            // 0..3
    const int wave = threadIdx.x >> 6;
    const int lane = threadIdx.x & 63;
    const int quad = lane >> 4;
    const int lq   = lane & 15;
    const int i0   = ib * 64;
    const int i    = i0 + wave * 16 + lq;
    const int colbase = js0 * KCOLS;

    // stage E slice (2048 cols per table) into LDS
    {
        const int m0 = threadIdx.x * 8;                   // 0..2040
        *(f32x4*)&lE[m0]              = *(const f32x4*)(E1 + colbase + m0);
        *(f32x4*)&lE[m0 + 4]          = *(const f32x4*)(E1 + colbase + m0 + 4);
        *(f32x4*)&lE[KCOLS + m0]      = *(const f32x4*)(E2 + colbase + m0);
        *(f32x4*)&lE[KCOLS + m0 + 4]  = *(const f32x4*)(E2 + colbase + m0 + 4);
    }

    const float dmax = __int_as_float(*dmax_bits);
    const float si  = s_arr[i];
    const float tbv = si + dmax;
    const float mi  = fmaxf(tbv, SLOPE * tbv);   // row-logit upper bound
    const float Aw  = __expf(si - mi);           // e^{k1}
    const float Bw  = __expf(SLOPE * si - mi);   // e^{k2}

    // bitmask row for this lane's A-fragment row (quad selects bits, not addr)
    const unsigned char* mrow = gbm + (size_t)i * (GN / 8);

    f32x4 acc0 = {0,0,0,0}, acc1 = {0,0,0,0}, acc2 = {0,0,0,0}, acc3 = {0,0,0,0};
    f32x4 acc4 = {0,0,0,0};              // row-sum via ones-MFMA
    bf16x8 ones;
    #pragma unroll
    for (int q = 0; q < 8; ++q) ones[q] = (short)0x3F80;

    // preload u=0
    unsigned bm = *(const unsigned*)(mrow + (colbase >> 3));
    bf16x8 b0, b1, b2, b3;
    {
        const ushort* nb = WhTp + ((size_t)(colbase >> 3) + quad) * 512;
        b0 = *(const bf16x8*)(nb + ( 0 + lq) * 8);
        b1 = *(const bf16x8*)(nb + (16 + lq) * 8);
        b2 = *(const bf16x8*)(nb + (32 + lq) * 8);
        b3 = *(const bf16x8*)(nb + (48 + lq) * 8);
    }
    __syncthreads();   // lE staged

    #pragma unroll 4
    for (int u = 0; u < KITER; ++u) {
        // rolling lag-1 prefetch (all L2-resident; ~200cy)
        const int un   = (u < KITER - 1) ? u + 1 : u;
        const int ncol = colbase + un * 32;
        const unsigned nbm = *(const unsigned*)(mrow + (ncol >> 3));
        const ushort* nb = WhTp + ((size_t)(ncol >> 3) + quad) * 512;
        const bf16x8 nb0 = *(const bf16x8*)(nb + ( 0 + lq) * 8);
        const bf16x8 nb1 = *(const bf16x8*)(nb + (16 + lq) * 8);
        const bf16x8 nb2 = *(const bf16x8*)(nb + (32 + lq) * 8);
        const bf16x8 nb3 = *(const bf16x8*)(nb + (48 + lq) * 8);
        // E slices from LDS
        const float* pe = lE + u * 32 + quad * 8;
        const f32x4 e1a = *(const f32x4*)pe;
        const f32x4 e1b = *(const f32x4*)(pe + 4);
        const f32x4 e2a = *(const f32x4*)(pe + KCOLS);
        const f32x4 e2b = *(const f32x4*)(pe + KCOLS + 4);
        // weights: w = bit ? max(Aw*E1, Bw*E2) : 0   (separable exp)
        const unsigned m8 = (bm >> (quad * 8)) & 0xffu;
        float w[8];
        #pragma unroll
        for (int q = 0; q < 4; ++q) {
            const float w0 = fmaxf(Aw * e1a[q], Bw * e2a[q]);
            const float w1 = fmaxf(Aw * e1b[q], Bw * e2b[q]);
            w[q]     = ((m8 >> q) & 1u) ? w0 : 0.f;
            w[4 + q] = ((m8 >> (4 + q)) & 1u) ? w1 : 0.f;
        }
        union { bf16x8 v; __hip_bfloat162 h[4]; } af;
        #pragma unroll
        for (int q = 0; q < 4; ++q)
            af.h[q] = __float22bfloat162_rn(make_float2(w[2 * q], w[2 * q + 1]));
        acc0 = __builtin_amdgcn_mfma_f32_16x16x32_bf16(af.v, b0, acc0, 0, 0, 0);
        acc1 = __builtin_amdgcn_mfma_f32_16x16x32_bf16(af.v, b1, acc1, 0, 0, 0);
        acc2 = __builtin_amdgcn_mfma_f32_16x16x32_bf16(af.v, b2, acc2, 0, 0, 0);
        acc3 = __builtin_amdgcn_mfma_f32_16x16x32_bf16(af.v, b3, acc3, 0, 0, 0);
        acc4 = __builtin_amdgcn_mfma_f32_16x16x32_bf16(af.v, ones, acc4, 0, 0, 0);
        bm = nbm; b0 = nb0; b1 = nb1; b2 = nb2; b3 = nb3;
    }

    // epilogue: plain stores to this block's DISJOINT slab (no atomics)
    const int orow = i0 + wave * 16 + quad * 4;
    float* pslab = part + ((size_t)js0 * GN + orow) * ODIM;
    if (lq == 0) {
        #pragma unroll
        for (int r = 0; r < 4; ++r) prs[js0 * GN + orow + r] = acc4[r];
    }
    #pragma unroll
    for (int r = 0; r < 4; ++r) {
        pslab[r * ODIM +  0 + lq] = acc0[r];
        pslab[r * ODIM + 16 + lq] = acc1[r];
        pslab[r * ODIM + 32 + lq] = acc2[r];
        pslab[r * ODIM + 48 + lq] = acc3[r];
    }
}

// Kernel 3: out = (sum_k part[k]) / (sum_k prs[k]), dtype per flag
extern "C" __global__ __launch_bounds__(256)
void gat_final(const float* __restrict__ part, const float* __restrict__ prs,
               const int* __restrict__ flag, void* __restrict__ out)
{
    const int idx = blockIdx.x * 256 + threadIdx.x;
    const int row = idx >> 6;
    float a = 0.f, s = 0.f;
    #pragma unroll
    for (int k = 0; k < KSPL; ++k) {
        a += part[(size_t)k * GN * ODIM + idx];
        s += prs[k * GN + row];
    }
    const float v = a / s;
    if (*flag) ((float*)out)[idx] = v;
    else       ((ushort*)out)[idx] = f2bf(v);
}

extern "C" void kernel_launch(void* const* d_in, const int* in_sizes, int n_in,
                              void* d_out, int out_size, void* d_ws, size_t ws_size,
                              hipStream_t stream)
{
    const void* x     = d_in[0];
    const int*  adj   = (const int*)d_in[1];
    const void* W     = d_in[2];
    const void* a_src = d_in[3];
    const void* a_dst = d_in[4];

    char* ws = (char*)d_ws;
    size_t off = 0;
    int* dmax_bits = (int*)(ws + off);  off += 128;
    int* dflag = (int*)(ws + off);      off += 128;
    size_t zero_bytes = off;                                               // 256 B only
    float* s_arr = (float*)(ws + off);  off += (size_t)GN * 4;
    float* E1    = (float*)(ws + off);  off += (size_t)GN * 4;
    float* E2    = (float*)(ws + off);  off += (size_t)GN * 4;
    ushort* WhTp = (ushort*)(ws + off); off += (size_t)ODIM * GN * 2;      // 1 MB
    unsigned* gbm = (unsigned*)(ws + off); off += (size_t)GN * (GN / 8);   // 8 MB
    float* part  = (float*)(ws + off);  off += (size_t)KSPL * GN * ODIM * 4; // 8 MB
    float* prs   = (float*)(ws + off);  off += (size_t)KSPL * GN * 4;      // 128 KB

    hipMemsetAsync(ws, 0, zero_bytes, stream);
    gat_pack<<<GN * (GN / 32) / 256, 256, 0, stream>>>(adj, gbm);          // 8192 blocks
    gat_proj<<<GN / 64, 256, 0, stream>>>(x, W, a_src, a_dst,
                                          WhTp, s_arr, E1, E2, dmax_bits, dflag);
    gat_attn<<<128 * KSPL, 256, 0, stream>>>((const unsigned char*)gbm, WhTp,
                                             s_arr, E1, E2, dmax_bits,
                                             part, prs);
    gat_final<<<GN * ODIM / 256, 256, 0, stream>>>(part, prs, dflag, d_out);
}

// Round 5
// 437.716 us; speedup vs baseline: 1.0529x; 1.0399x over previous
//
#include <hip/hip_runtime.h>
#include <hip/hip_bf16.h>

#define GN 8192
#define IN_DIM 512
#define ODIM 64
#define SLOPE 0.2f
#define KSPL 16                // column split: 16 disjoint partial slabs
#define CB (GN / KSPL)         // 512 cols per attn block
#define CITER (CB / 32)        // 16 col-iters per block
#define LSTRIDE 68             // LDS mask row stride bytes (17 words, conflict-free)

typedef __attribute__((ext_vector_type(4))) float  f32x4;
typedef __attribute__((ext_vector_type(4))) int    i32x4;
typedef __attribute__((ext_vector_type(8))) short  bf16x8;
typedef __attribute__((ext_vector_type(4))) unsigned short u16x4;

static __device__ __forceinline__ float bf2f(unsigned short u) {
    return __uint_as_float(((unsigned)u) << 16);
}
static __device__ __forceinline__ unsigned short f2bf(float f) {
    union { float f; unsigned u; } c; c.f = f;
    unsigned b = c.u;
    return (unsigned short)((b + 0x7fffu + ((b >> 16) & 1u)) >> 16);  // RNE
}

// load 8 contiguous elements as bf16x8, from either wire dtype
static __device__ __forceinline__ bf16x8 load8(const void* p, size_t off, int f32) {
    if (f32) {
        f32x4 lo = *(const f32x4*)((const float*)p + off);
        f32x4 hi = *(const f32x4*)((const float*)p + off + 4);
        bf16x8 r;
        #pragma unroll
        for (int q = 0; q < 4; ++q) {
            r[q]     = (short)f2bf(lo[q]);
            r[4 + q] = (short)f2bf(hi[q]);
        }
        return r;
    }
    return *(const bf16x8*)((const ushort*)p + off);
}

// Kernel 1 (MFMA GEMM): Wh = x@W^T. Epilogue writes WhTp in B-operand-native
// layout; s_arr; E1=e^{d}, E2=e^{0.2d} (separable exp: exp monotone =>
// exp(max(d+k1,0.2d+k2)) = max(e^{k1}E1, e^{k2}E2)); dmax; dflag.
extern "C" __global__ __launch_bounds__(256)
void gat_proj(const void* __restrict__ x_, const void* __restrict__ W_,
              const void* __restrict__ as_, const void* __restrict__ ad_,
              ushort* __restrict__ WhTp, float* __restrict__ s_arr,
              float* __restrict__ E1, float* __restrict__ E2,
              int* __restrict__ dmax_bits, int* __restrict__ dflag)
{
    const int wave = threadIdx.x >> 6;
    const int lane = threadIdx.x & 63;
    unsigned xw = ((const unsigned*)x_)[lane];
    unsigned ef = (xw >> 23) & 0xffu;
    unsigned long long vt = __ballot(ef > 60u && ef < 180u);
    const int f32 = (__popcll(vt) >= 32) ? 1 : 0;
    if (blockIdx.x == 0 && threadIdx.x == 0) *dflag = f32;

    const int quad = lane >> 4;
    const int lq   = lane & 15;
    const int i0   = blockIdx.x * 64 + wave * 16;

    f32x4 acc[4] = {{0,0,0,0},{0,0,0,0},{0,0,0,0},{0,0,0,0}};
    const size_t arow = (size_t)(i0 + lq) * IN_DIM;
    #pragma unroll 2
    for (int k0 = 0; k0 < IN_DIM; k0 += 32) {
        const int kk = k0 + quad * 8;
        bf16x8 a  = load8(x_, arow + kk, f32);
        bf16x8 b0 = load8(W_, (size_t)( 0 + lq) * IN_DIM + kk, f32);
        bf16x8 b1 = load8(W_, (size_t)(16 + lq) * IN_DIM + kk, f32);
        bf16x8 b2 = load8(W_, (size_t)(32 + lq) * IN_DIM + kk, f32);
        bf16x8 b3 = load8(W_, (size_t)(48 + lq) * IN_DIM + kk, f32);
        acc[0] = __builtin_amdgcn_mfma_f32_16x16x32_bf16(a, b0, acc[0], 0, 0, 0);
        acc[1] = __builtin_amdgcn_mfma_f32_16x16x32_bf16(a, b1, acc[1], 0, 0, 0);
        acc[2] = __builtin_amdgcn_mfma_f32_16x16x32_bf16(a, b2, acc[2], 0, 0, 0);
        acc[3] = __builtin_amdgcn_mfma_f32_16x16x32_bf16(a, b3, acc[3], 0, 0, 0);
    }
    float av_s[4], av_d[4];
    #pragma unroll
    for (int t = 0; t < 4; ++t) {
        const int n = t * 16 + lq;
        av_s[t] = f32 ? ((const float*)as_)[n] : bf2f(((const ushort*)as_)[n]);
        av_d[t] = f32 ? ((const float*)ad_)[n] : bf2f(((const ushort*)ad_)[n]);
    }
    #pragma unroll
    for (int t = 0; t < 4; ++t) {
        u16x4 pk;
        #pragma unroll
        for (int r = 0; r < 4; ++r) pk[r] = f2bf(acc[t][r]);
        const size_t hw = ((size_t)((i0 >> 3) + (quad >> 1)) * 64 + t * 16 + lq) * 8
                          + (quad & 1) * 4;
        *(u16x4*)(WhTp + hw) = pk;
    }
    float ps[4], pd[4];
    #pragma unroll
    for (int r = 0; r < 4; ++r) {
        float s = 0.f, d = 0.f;
        #pragma unroll
        for (int t = 0; t < 4; ++t) {
            s = fmaf(acc[t][r], av_s[t], s);
            d = fmaf(acc[t][r], av_d[t], d);
        }
        #pragma unroll
        for (int off = 1; off < 16; off <<= 1) {
            s += __shfl_xor(s, off);
            d += __shfl_xor(d, off);
        }
        ps[r] = s; pd[r] = d;
    }
    if (lq == 0) {
        float dmx = -1e30f;
        #pragma unroll
        for (int r = 0; r < 4; ++r) {
            const int n = i0 + quad * 4 + r;
            const float dv = pd[r];
            s_arr[n] = ps[r];
            E1[n] = __expf(fminf(dv, 87.f));        // e^{dj} (clamped vs inf)
            E2[n] = __expf(SLOPE * dv);             // e^{0.2 dj}
            dmx = fmaxf(dmx, dv);
        }
        if (dmx > 0.f) atomicMax(dmax_bits, __float_as_int(dmx));
    }
}

// Kernel 2: fused attention, zero in-loop global loads. 2048 blocks =
// 128 ib x 16 js (consecutive b share ib -> concurrent blocks cover whole
// adj rows for DRAM locality). Per block (64 rows x 512 cols):
//   PROLOGUE (bulk, before one barrier):
//     - adj rows: one full 2KB row-chunk per load instruction (champion's
//       coalescing), bit-packed into LDS mask mb[64][68].
//     - WhTp fragment slab: 64KB contiguous copy to LDS.
//     - E1/E2 slices: 4KB to LDS.
//   LOOP (16 iters): mask u32 (LDS) + 4x ds_read_b128 B-frags (LDS) +
//     broadcast E (LDS) + ~45 VALU + 5 MFMA. NO vmem -> the vmcnt-drain
//     stall class of R0-R4 is structurally impossible.
// LDS 74KB -> 2 blocks/CU: one block's prologue HBM burst overlaps the
// other's compute phase. Epilogue: plain stores to disjoint slab part[js].
extern "C" __global__ __launch_bounds__(256)
void gat_attn(const int* __restrict__ adj, const ushort* __restrict__ WhTp,
              const float* __restrict__ s_arr,
              const float* __restrict__ E1, const float* __restrict__ E2,
              const int* __restrict__ dmax_bits,
              float* __restrict__ part, float* __restrict__ prs)
{
    __shared__ ushort lB[CB * 64];              // 64 KB, fragment-native
    __shared__ float  lE[2 * CB];               // 4 KB: [0..511]=E1, [512..]=E2
    __shared__ unsigned char mb[64 * LSTRIDE];  // 4.25 KB bitmask

    const int b    = blockIdx.x;        // 0..2047
    const int ib   = b >> 4;            // 0..127
    const int js   = b & 15;            // 0..15
    const int wave = threadIdx.x >> 6;
    const int lane = threadIdx.x & 63;
    const int quad = lane >> 4;
    const int lq   = lane & 15;
    const int i0   = ib * 64;
    const int i    = i0 + wave * 16 + lq;
    const int colbase = js * CB;

    // --- stage WhTp fragment slab (contiguous 64KB for cols [colbase,+512))
    {
        const f32x4* src = (const f32x4*)(WhTp + (size_t)(colbase >> 3) * 512);
        f32x4* dst = (f32x4*)lB;
        #pragma unroll
        for (int c = 0; c < 16; ++c)
            dst[c * 256 + threadIdx.x] = src[c * 256 + threadIdx.x];
    }
    // --- stage E slices
    if (threadIdx.x < 128)
        ((f32x4*)lE)[threadIdx.x] = ((const f32x4*)(E1 + colbase))[threadIdx.x];
    else
        ((f32x4*)(lE + CB))[threadIdx.x - 128] =
            ((const f32x4*)(E2 + colbase))[threadIdx.x - 128];
    // --- adj rows -> bitmask (per step: 64 lanes x 32B = one 2KB row chunk)
    #pragma unroll
    for (int rr = 0; rr < 16; ++rr) {
        const int li2 = wave * 16 + rr;
        const int* p = adj + (size_t)(i0 + li2) * GN + colbase + lane * 8;
        const i32x4 va = ((const i32x4*)p)[0];
        const i32x4 vb = ((const i32x4*)p)[1];
        unsigned byte = 0;
        #pragma unroll
        for (int q = 0; q < 4; ++q) {
            byte |= (va[q] > 0 ? 1u : 0u) << q;
            byte |= (vb[q] > 0 ? 1u : 0u) << (4 + q);
        }
        mb[li2 * LSTRIDE + lane] = (unsigned char)byte;
    }

    const float dmax = __int_as_float(*dmax_bits);
    const float si  = s_arr[i];
    const float tbv = si + dmax;
    const float mi  = fmaxf(tbv, SLOPE * tbv);   // row-logit upper bound
    const float Aw  = __expf(si - mi);           // e^{k1}
    const float Bw  = __expf(SLOPE * si - mi);   // e^{k2}

    f32x4 acc0 = {0,0,0,0}, acc1 = {0,0,0,0}, acc2 = {0,0,0,0}, acc3 = {0,0,0,0};
    f32x4 acc4 = {0,0,0,0};              // row-sum via ones-MFMA
    bf16x8 ones;
    #pragma unroll
    for (int q = 0; q < 8; ++q) ones[q] = (short)0x3F80;

    __syncthreads();   // everything staged

    const int li = wave * 16 + lq;
    #pragma unroll 4
    for (int u = 0; u < CITER; ++u) {
        // mask word: row li, cols u*32.. (16 distinct addrs/wave, stride 68 ->
        // banks (17*li+u)%32 all distinct -> conflict-free broadcast)
        const unsigned bw = *(const unsigned*)&mb[li * LSTRIDE + u * 4];
        // B fragments from LDS
        const ushort* bb = lB + (size_t)(u * 4 + quad) * 512;
        const bf16x8 b0 = *(const bf16x8*)(bb + ( 0 + lq) * 8);
        const bf16x8 b1 = *(const bf16x8*)(bb + (16 + lq) * 8);
        const bf16x8 b2 = *(const bf16x8*)(bb + (32 + lq) * 8);
        const bf16x8 b3 = *(const bf16x8*)(bb + (48 + lq) * 8);
        // E slices (broadcast within quads)
        const float* pe = lE + u * 32 + quad * 8;
        const f32x4 e1a = *(const f32x4*)pe;
        const f32x4 e1b = *(const f32x4*)(pe + 4);
        const f32x4 e2a = *(const f32x4*)(pe + CB);
        const f32x4 e2b = *(const f32x4*)(pe + CB + 4);
        // weights: w = bit ? max(Aw*E1, Bw*E2) : 0   (separable exp)
        const unsigned m8 = (bw >> (quad * 8)) & 0xffu;
        float w[8];
        #pragma unroll
        for (int q = 0; q < 4; ++q) {
            const float w0 = fmaxf(Aw * e1a[q], Bw * e2a[q]);
            const float w1 = fmaxf(Aw * e1b[q], Bw * e2b[q]);
            w[q]     = ((m8 >> q) & 1u) ? w0 : 0.f;
            w[4 + q] = ((m8 >> (4 + q)) & 1u) ? w1 : 0.f;
        }
        union { bf16x8 v; __hip_bfloat162 h[4]; } af;
        #pragma unroll
        for (int q = 0; q < 4; ++q)
            af.h[q] = __float22bfloat162_rn(make_float2(w[2 * q], w[2 * q + 1]));
        acc0 = __builtin_amdgcn_mfma_f32_16x16x32_bf16(af.v, b0, acc0, 0, 0, 0);
        acc1 = __builtin_amdgcn_mfma_f32_16x16x32_bf16(af.v, b1, acc1, 0, 0, 0);
        acc2 = __builtin_amdgcn_mfma_f32_16x16x32_bf16(af.v, b2, acc2, 0, 0, 0);
        acc3 = __builtin_amdgcn_mfma_f32_16x16x32_bf16(af.v, b3, acc3, 0, 0, 0);
        acc4 = __builtin_amdgcn_mfma_f32_16x16x32_bf16(af.v, ones, acc4, 0, 0, 0);
    }

    // epilogue: plain stores to this block's DISJOINT slab (no atomics)
    const int orow = i0 + wave * 16 + quad * 4;
    float* pslab = part + ((size_t)js * GN + orow) * ODIM;
    if (lq == 0) {
        #pragma unroll
        for (int r = 0; r < 4; ++r) prs[js * GN + orow + r] = acc4[r];
    }
    #pragma unroll
    for (int r = 0; r < 4; ++r) {
        pslab[r * ODIM +  0 + lq] = acc0[r];
        pslab[r * ODIM + 16 + lq] = acc1[r];
        pslab[r * ODIM + 32 + lq] = acc2[r];
        pslab[r * ODIM + 48 + lq] = acc3[r];
    }
}

// Kernel 3: out = (sum_k part[k]) / (sum_k prs[k]), dtype per flag
extern "C" __global__ __launch_bounds__(256)
void gat_final(const float* __restrict__ part, const float* __restrict__ prs,
               const int* __restrict__ flag, void* __restrict__ out)
{
    const int idx = blockIdx.x * 256 + threadIdx.x;
    const int row = idx >> 6;
    float a = 0.f, s = 0.f;
    #pragma unroll
    for (int k = 0; k < KSPL; ++k) {
        a += part[(size_t)k * GN * ODIM + idx];
        s += prs[k * GN + row];
    }
    const float v = a / s;
    if (*flag) ((float*)out)[idx] = v;
    else       ((ushort*)out)[idx] = f2bf(v);
}

extern "C" void kernel_launch(void* const* d_in, const int* in_sizes, int n_in,
                              void* d_out, int out_size, void* d_ws, size_t ws_size,
                              hipStream_t stream)
{
    const void* x     = d_in[0];
    const int*  adj   = (const int*)d_in[1];
    const void* W     = d_in[2];
    const void* a_src = d_in[3];
    const void* a_dst = d_in[4];

    char* ws = (char*)d_ws;
    size_t off = 0;
    int* dmax_bits = (int*)(ws + off);  off += 128;
    int* dflag = (int*)(ws + off);      off += 128;
    size_t zero_bytes = off;                                               // 256 B only
    float* s_arr = (float*)(ws + off);  off += (size_t)GN * 4;
    float* E1    = (float*)(ws + off);  off += (size_t)GN * 4;
    float* E2    = (float*)(ws + off);  off += (size_t)GN * 4;
    ushort* WhTp = (ushort*)(ws + off); off += (size_t)ODIM * GN * 2;      // 1 MB
    float* part  = (float*)(ws + off);  off += (size_t)KSPL * GN * ODIM * 4; // 32 MB
    float* prs   = (float*)(ws + off);  off += (size_t)KSPL * GN * 4;      // 512 KB

    hipMemsetAsync(ws, 0, zero_bytes, stream);
    gat_proj<<<GN / 64, 256, 0, stream>>>(x, W, a_src, a_dst,
                                          WhTp, s_arr, E1, E2, dmax_bits, dflag);
    gat_attn<<<128 * KSPL, 256, 0, stream>>>(adj, WhTp, s_arr, E1, E2,
                                             dmax_bits, part, prs);
    gat_final<<<GN * ODIM / 256, 256, 0, stream>>>(part, prs, dflag, d_out);
}

// Round 6
// 423.924 us; speedup vs baseline: 1.0872x; 1.0325x over previous
//
#include <hip/hip_runtime.h>
#include <hip/hip_bf16.h>

#define GN 8192
#define IN_DIM 512
#define ODIM 64
#define SLOPE 0.2f
#define JSPLIT 16
#define JCH (GN / JSPLIT)      // 512 cols per tile
#define LSTRIDE 68             // LDS mask row stride bytes (17 words -> conflict-free)
#define NTILE 4                // tiles per block (js0 + 4t, traversed descending)

typedef __attribute__((ext_vector_type(4))) float  f32x4;
typedef __attribute__((ext_vector_type(4))) int    i32x4;
typedef __attribute__((ext_vector_type(8))) short  bf16x8;
typedef __attribute__((ext_vector_type(4))) unsigned short u16x4;

static __device__ __forceinline__ float bf2f(unsigned short u) {
    return __uint_as_float(((unsigned)u) << 16);
}
static __device__ __forceinline__ unsigned short f2bf(float f) {
    union { float f; unsigned u; } c; c.f = f;
    unsigned b = c.u;
    return (unsigned short)((b + 0x7fffu + ((b >> 16) & 1u)) >> 16);  // RNE
}

// load 8 contiguous elements as bf16x8, from either wire dtype
static __device__ __forceinline__ bf16x8 load8(const void* p, size_t off, int f32) {
    if (f32) {
        f32x4 lo = *(const f32x4*)((const float*)p + off);
        f32x4 hi = *(const f32x4*)((const float*)p + off + 4);
        bf16x8 r;
        #pragma unroll
        for (int q = 0; q < 4; ++q) {
            r[q]     = (short)f2bf(lo[q]);
            r[4 + q] = (short)f2bf(hi[q]);
        }
        return r;
    }
    return *(const bf16x8*)((const ushort*)p + off);
}

// col of flattened iter u (tile u>>4 descending, 32-col chunk (u&15) inside)
static __device__ __forceinline__ int colof(int js0, int u) {
    return (js0 + 4 * (NTILE - 1 - (u >> 4))) * JCH + (u & 15) * 32;
}

// Kernel 1 (MFMA GEMM): Wh = x@W^T. Epilogue writes WhTp in B-operand-native
// layout (16B unit U(jblk,n) = Wh[jblk*8+0..7][n]); s_arr; E1=e^{d},
// E2=e^{0.2d} (separable exp: exp monotone => exp(max(d+k1,0.2d+k2)) =
// max(e^{k1}E1, e^{k2}E2)); dmax; dflag; zero-inits accum/lsum (kernel
// boundary orders it before gat_attn's atomics).
extern "C" __global__ __launch_bounds__(256)
void gat_proj(const void* __restrict__ x_, const void* __restrict__ W_,
              const void* __restrict__ as_, const void* __restrict__ ad_,
              ushort* __restrict__ WhTp, float* __restrict__ s_arr,
              float* __restrict__ E1, float* __restrict__ E2,
              int* __restrict__ dmax_bits, int* __restrict__ dflag,
              float* __restrict__ accum, float* __restrict__ lsum)
{
    {
        f32x4 z = {0.f, 0.f, 0.f, 0.f};
        f32x4* ap = (f32x4*)(accum + (size_t)blockIdx.x * 4096);
        #pragma unroll
        for (int k = 0; k < 4; ++k) ap[k * 256 + threadIdx.x] = z;
        if (threadIdx.x < 64) lsum[blockIdx.x * 64 + threadIdx.x] = 0.f;
    }
    const int wave = threadIdx.x >> 6;
    const int lane = threadIdx.x & 63;
    unsigned xw = ((const unsigned*)x_)[lane];
    unsigned ef = (xw >> 23) & 0xffu;
    unsigned long long vt = __ballot(ef > 60u && ef < 180u);
    const int f32 = (__popcll(vt) >= 32) ? 1 : 0;
    if (blockIdx.x == 0 && threadIdx.x == 0) *dflag = f32;

    const int quad = lane >> 4;
    const int lq   = lane & 15;
    const int i0   = blockIdx.x * 64 + wave * 16;

    f32x4 acc[4] = {{0,0,0,0},{0,0,0,0},{0,0,0,0},{0,0,0,0}};
    const size_t arow = (size_t)(i0 + lq) * IN_DIM;
    #pragma unroll 2
    for (int k0 = 0; k0 < IN_DIM; k0 += 32) {
        const int kk = k0 + quad * 8;
        bf16x8 a  = load8(x_, arow + kk, f32);
        bf16x8 b0 = load8(W_, (size_t)( 0 + lq) * IN_DIM + kk, f32);
        bf16x8 b1 = load8(W_, (size_t)(16 + lq) * IN_DIM + kk, f32);
        bf16x8 b2 = load8(W_, (size_t)(32 + lq) * IN_DIM + kk, f32);
        bf16x8 b3 = load8(W_, (size_t)(48 + lq) * IN_DIM + kk, f32);
        acc[0] = __builtin_amdgcn_mfma_f32_16x16x32_bf16(a, b0, acc[0], 0, 0, 0);
        acc[1] = __builtin_amdgcn_mfma_f32_16x16x32_bf16(a, b1, acc[1], 0, 0, 0);
        acc[2] = __builtin_amdgcn_mfma_f32_16x16x32_bf16(a, b2, acc[2], 0, 0, 0);
        acc[3] = __builtin_amdgcn_mfma_f32_16x16x32_bf16(a, b3, acc[3], 0, 0, 0);
    }
    float av_s[4], av_d[4];
    #pragma unroll
    for (int t = 0; t < 4; ++t) {
        const int n = t * 16 + lq;
        av_s[t] = f32 ? ((const float*)as_)[n] : bf2f(((const ushort*)as_)[n]);
        av_d[t] = f32 ? ((const float*)ad_)[n] : bf2f(((const ushort*)ad_)[n]);
    }
    #pragma unroll
    for (int t = 0; t < 4; ++t) {
        u16x4 pk;
        #pragma unroll
        for (int r = 0; r < 4; ++r) pk[r] = f2bf(acc[t][r]);
        const size_t hw = ((size_t)((i0 >> 3) + (quad >> 1)) * 64 + t * 16 + lq) * 8
                          + (quad & 1) * 4;
        *(u16x4*)(WhTp + hw) = pk;
    }
    float ps[4], pd[4];
    #pragma unroll
    for (int r = 0; r < 4; ++r) {
        float s = 0.f, d = 0.f;
        #pragma unroll
        for (int t = 0; t < 4; ++t) {
            s = fmaf(acc[t][r], av_s[t], s);
            d = fmaf(acc[t][r], av_d[t], d);
        }
        #pragma unroll
        for (int off = 1; off < 16; off <<= 1) {
            s += __shfl_xor(s, off);
            d += __shfl_xor(d, off);
        }
        ps[r] = s; pd[r] = d;
    }
    if (lq == 0) {
        float dmx = -1e30f;
        #pragma unroll
        for (int r = 0; r < 4; ++r) {
            const int n = i0 + quad * 4 + r;
            const float dv = pd[r];
            s_arr[n] = ps[r];
            E1[n] = __expf(fminf(dv, 87.f));        // e^{dj} (clamped vs inf)
            E2[n] = __expf(SLOPE * dv);             // e^{0.2 dj}
            dmx = fmaxf(dmx, dv);
        }
        if (dmx > 0.f) atomicMax(dmax_bits, __float_as_int(dmx));
    }
}

// Kernel 2: fused attention = the 424us champion EXACTLY (512 blocks =
// 128 ib x 4 js0, NTILE=4 descending tiles, reversed ib, ring-6/pack-lag-5
// adj stream, LDS mask, atomic epilogue) with ONE surgical change:
// the per-iter d_arr loads + 8 expf are replaced by LDS-staged separable-exp
// tables: w = mask ? max(Aw*E1[j], Bw*E2[j]) : 0 with Aw=e^{si-mi},
// Bw=e^{0.2si-mi}. Effects: zero transcendentals in the loop; per-iter vmem
// operand queue shrinks 6->4 loads (shallower drains of the adj ring).
// Everything else byte-identical to the champion.
extern "C" __global__ __launch_bounds__(256)
void gat_attn(const int* __restrict__ adj, const ushort* __restrict__ WhTp,
              const float* __restrict__ s_arr,
              const float* __restrict__ E1, const float* __restrict__ E2,
              const int* __restrict__ dmax_bits,
              float* __restrict__ accum, float* __restrict__ lsum)
{
    __shared__ unsigned char mb[2][64 * LSTRIDE];
    __shared__ float lE[2 * NTILE * 512];   // 16 KB: [0..2047]=E1, [2048..]=E2
    const int b    = blockIdx.x;        // 0..511
    const int ib   = 127 - (b & 127);   // reversed: high rows first
    const int js0  = b >> 7;            // 0..3
    const int wave = threadIdx.x >> 6;
    const int lane = threadIdx.x & 63;
    const int quad = lane >> 4;
    const int lq   = lane & 15;
    const int i0   = ib * 64;
    const int li   = wave * 16 + lq;
    const int i    = i0 + li;
    const float dmax = __int_as_float(*dmax_bits);
    const float si = s_arr[i];
    const float tbv = si + dmax;
    const float mi = fmaxf(tbv, SLOPE * tbv);   // row-logit upper bound
    const float Aw = __expf(si - mi);           // e^{k1}
    const float Bw = __expf(SLOPE * si - mi);   // e^{k2}

    // stage E tables (this js0's 4 tiles, flattened-u order) into LDS.
    // Issued BEFORE the adj prologue: their internal vmcnt waits drain only
    // themselves, never the adj ring.
    {
        const int m0 = threadIdx.x * 8;                   // 0..2040
        const int gcol = colof(js0, m0 >> 5) + (m0 & 31);
        *(f32x4*)&lE[m0]            = *(const f32x4*)(E1 + gcol);
        *(f32x4*)&lE[m0 + 4]        = *(const f32x4*)(E1 + gcol + 4);
        *(f32x4*)&lE[2048 + m0]     = *(const f32x4*)(E2 + gcol);
        *(f32x4*)&lE[2048 + m0 + 4] = *(const f32x4*)(E2 + gcol + 4);
    }

    const size_t adjbase = (size_t)i0 * GN + lane * 8;

    i32x4 ra[6], rb[6];
    auto issue = [&](int c, int jb) {
        const int* rp = adj + adjbase + (size_t)(c * 4 + wave) * GN + jb;
        ra[c % 6] = ((const i32x4*)rp)[0];
        rb[c % 6] = ((const i32x4*)rp)[1];
    };
    auto pack = [&](int c, int bufsel) {
        const i32x4 va = ra[c % 6], vb = rb[c % 6];
        unsigned byte = 0;
        #pragma unroll
        for (int q = 0; q < 4; ++q) {
            byte |= (va[q] > 0 ? 1u : 0u) << q;
            byte |= (vb[q] > 0 ? 1u : 0u) << (4 + q);
        }
        mb[bufsel][(c * 4 + wave) * LSTRIDE + lane] = (unsigned char)byte;
    };

    f32x4 acc0 = {0,0,0,0}, acc1 = {0,0,0,0}, acc2 = {0,0,0,0}, acc3 = {0,0,0,0};
    f32x4 acc4 = {0,0,0,0};             // row-sum via ones-MFMA
    bf16x8 ones;
    #pragma unroll
    for (int q = 0; q < 8; ++q) ones[q] = (short)0x3F80;

    // tile t processes columns js(t) = js0 + 4*(NTILE-1-t)  (descending)
    const int jb0 = (js0 + 4 * (NTILE - 1)) * JCH;

    // ---- prologue: stage tile 0 -> mb[0], lag-5 ring ----
    #pragma unroll
    for (int c = 0; c < 16; ++c) {
        issue(c, jb0);
        if (c >= 5) pack(c - 5, 0);
    }
    pack(11, 0); pack(12, 0); pack(13, 0); pack(14, 0); pack(15, 0);
    __syncthreads();

    // preload WhTp operands for tile 0, col-iter 0
    const ushort* bb0 = WhTp + ((size_t)(jb0 >> 3) + quad) * 512;
    bf16x8 b0 = *(const bf16x8*)(bb0 + ( 0 + lq) * 8);
    bf16x8 b1 = *(const bf16x8*)(bb0 + (16 + lq) * 8);
    bf16x8 b2 = *(const bf16x8*)(bb0 + (32 + lq) * 8);
    bf16x8 b3 = *(const bf16x8*)(bb0 + (48 + lq) * 8);

    #pragma unroll 1
    for (int t = 0; t < NTILE; ++t) {
        const int jb   = (js0 + 4 * (NTILE - 1 - t)) * JCH;
        const int jbn  = jb - 4 * JCH;          // next tile (descending)
        const bool more = (t < NTILE - 1);
        const int buf  = t & 1, nbuf = buf ^ 1;

        #pragma unroll
        for (int it = 0; it < 16; ++it) {
            const int u = t * 16 + it;
            // 1) rolling WhTp prefetch (issued before this iter's adj:
            //    its vmcnt wait never drains younger adj loads)
            const int jtb = (it < 15) ? jb : (more ? jbn : jb);
            const int itn = (it < 15) ? (it + 1) : 0;
            const ushort* nb = WhTp + ((size_t)(jtb >> 3) + itn * 4 + quad) * 512;
            bf16x8 nb0 = *(const bf16x8*)(nb + ( 0 + lq) * 8);
            bf16x8 nb1 = *(const bf16x8*)(nb + (16 + lq) * 8);
            bf16x8 nb2 = *(const bf16x8*)(nb + (32 + lq) * 8);
            bf16x8 nb3 = *(const bf16x8*)(nb + (48 + lq) * 8);
            // 2) issue next-tile adj chunk into the 6-deep ring
            if (more) issue(it, jbn);
            // 3) pack chunk it-5 (chunks it-4..it stay in flight: ~5 iter
            //    bodies of latency cover)
            if (more && it >= 5) pack(it - 5, nbuf);
            // 4) compute col-iter it; E from LDS (lgkmcnt, never drains vmem)
            unsigned bw = *(const unsigned*)(&mb[buf][li * LSTRIDE + it * 4]);
            const unsigned m8 = (bw >> (quad * 8)) & 0xffu;
            const float* pe = lE + u * 32 + quad * 8;
            const f32x4 e1a = *(const f32x4*)pe;
            const f32x4 e1b = *(const f32x4*)(pe + 4);
            const f32x4 e2a = *(const f32x4*)(pe + 2048);
            const f32x4 e2b = *(const f32x4*)(pe + 2052);
            float w[8];
            #pragma unroll
            for (int q = 0; q < 4; ++q) {
                const float w0 = fmaxf(Aw * e1a[q], Bw * e2a[q]);
                const float w1 = fmaxf(Aw * e1b[q], Bw * e2b[q]);
                w[q]     = (m8 & (1u << q))       ? w0 : 0.f;
                w[4 + q] = (m8 & (1u << (4 + q))) ? w1 : 0.f;
            }
            union { bf16x8 v; __hip_bfloat162 h[4]; } af;
            #pragma unroll
            for (int q = 0; q < 4; ++q)
                af.h[q] = __float22bfloat162_rn(make_float2(w[2 * q], w[2 * q + 1]));
            acc0 = __builtin_amdgcn_mfma_f32_16x16x32_bf16(af.v, b0, acc0, 0, 0, 0);
            acc1 = __builtin_amdgcn_mfma_f32_16x16x32_bf16(af.v, b1, acc1, 0, 0, 0);
            acc2 = __builtin_amdgcn_mfma_f32_16x16x32_bf16(af.v, b2, acc2, 0, 0, 0);
            acc3 = __builtin_amdgcn_mfma_f32_16x16x32_bf16(af.v, b3, acc3, 0, 0, 0);
            acc4 = __builtin_amdgcn_mfma_f32_16x16x32_bf16(af.v, ones, acc4, 0, 0, 0);
            b0 = nb0; b1 = nb1; b2 = nb2; b3 = nb3;
        }
        if (more) {
            pack(11, nbuf); pack(12, nbuf); pack(13, nbuf);
            pack(14, nbuf); pack(15, nbuf);
        }
        __syncthreads();
    }

    // epilogue: C/D col=lq, row=quad*4+r; acc4 holds row sums in every col
    const int orow = i0 + wave * 16 + quad * 4;
    if (lq == 0) {
        #pragma unroll
        for (int r = 0; r < 4; ++r) atomicAdd(&lsum[orow + r], acc4[r]);
    }
    #pragma unroll
    for (int r = 0; r < 4; ++r) {
        atomicAdd(&accum[(size_t)(orow + r) * ODIM +  0 + lq], acc0[r]);
        atomicAdd(&accum[(size_t)(orow + r) * ODIM + 16 + lq], acc1[r]);
        atomicAdd(&accum[(size_t)(orow + r) * ODIM + 32 + lq], acc2[r]);
        atomicAdd(&accum[(size_t)(orow + r) * ODIM + 48 + lq], acc3[r]);
    }
}

// Kernel 3: out = (accum / lsum), dtype per flag
extern "C" __global__ __launch_bounds__(256)
void gat_final(const float* __restrict__ accum, const float* __restrict__ lsum,
               const int* __restrict__ flag, void* __restrict__ out)
{
    const int idx = blockIdx.x * 256 + threadIdx.x;
    const float v = accum[idx] / lsum[idx >> 6];
    if (*flag) ((float*)out)[idx] = v;
    else       ((ushort*)out)[idx] = f2bf(v);
}

extern "C" void kernel_launch(void* const* d_in, const int* in_sizes, int n_in,
                              void* d_out, int out_size, void* d_ws, size_t ws_size,
                              hipStream_t stream)
{
    const void* x     = d_in[0];
    const int*  adj   = (const int*)d_in[1];
    const void* W     = d_in[2];
    const void* a_src = d_in[3];
    const void* a_dst = d_in[4];

    char* ws = (char*)d_ws;
    size_t off = 0;
    int* dmax_bits = (int*)(ws + off);  off += 128;
    int* dflag = (int*)(ws + off);      off += 128;
    size_t zero_bytes = off;                                               // 256 B only
    float* accum = (float*)(ws + off);  off += (size_t)GN * ODIM * 4;      // 2 MB (proj zeroes)
    float* lsum  = (float*)(ws + off);  off += (size_t)GN * 4;             // 32 KB (proj zeroes)
    float* s_arr = (float*)(ws + off);  off += (size_t)GN * 4;
    float* E1    = (float*)(ws + off);  off += (size_t)GN * 4;
    float* E2    = (float*)(ws + off);  off += (size_t)GN * 4;
    ushort* WhTp = (ushort*)(ws + off); off += (size_t)ODIM * GN * 2;      // 1 MB

    hipMemsetAsync(ws, 0, zero_bytes, stream);
    gat_proj<<<GN / 64, 256, 0, stream>>>(x, W, a_src, a_dst,
                                          WhTp, s_arr, E1, E2, dmax_bits, dflag,
                                          accum, lsum);
    gat_attn<<<512, 256, 0, stream>>>(adj, WhTp, s_arr, E1, E2,
                                      dmax_bits, accum, lsum);
    gat_final<<<GN * ODIM / 256, 256, 0, stream>>>(accum, lsum, dflag, d_out);
}